// Round 2
// baseline (352.126 us; speedup 1.0000x reference)
//
#include <hip/hip_runtime.h>
#include <math.h>

#define BATCH 8192
#define DIM 1024
#define NCLS 1000
#define NPAD 1024         // padded class rows for the bf16 center matrix
#define NPAIRS 499500.0f  // 1000*999/2
#define INTER_TILES 136   // 16*17/2 upper-triangle 64x64 tiles (placed FIRST)
#define INTRA_BLOCKS (BATCH / 4)
#define GRID_B (INTER_TILES + INTRA_BLOCKS)
#define MAXROWS 192       // max rows per class we track (Poisson mean 8.2, max ~30)

typedef float  f32x4  __attribute__((ext_vector_type(4)));
typedef short  bf16x8 __attribute__((ext_vector_type(8)));

// ---------------- helpers ----------------

__device__ inline float waveAllReduceAdd(float x) {
  #pragma unroll
  for (int m = 32; m > 0; m >>= 1) x += __shfl_xor(x, m);
  return x;
}

// block (256 thr) reduce, broadcast; sm >= 8 floats
__device__ inline float blockReduce1(float x, float* sm) {
  x = waveAllReduceAdd(x);
  int lane = threadIdx.x & 63, wid = threadIdx.x >> 6;
  __syncthreads();
  if (lane == 0) sm[wid] = x;
  __syncthreads();
  return sm[0] + sm[1] + sm[2] + sm[3];
}

__device__ inline unsigned short f2bf(float f) {
  unsigned int u = __float_as_uint(f);
  u += 0x7FFFu + ((u >> 16) & 1u);  // RNE
  return (unsigned short)(u >> 16);
}

// ---------------- K1: center update with in-kernel row selection -------------
// Block c scans the 32KB label array (L2-broadcast across the 1024 blocks) and
// collects its class's row indices into LDS — replaces the serial 1-block
// hist/scan/scatter kernel. Then batched 8-rows-at-a-time normalized
// accumulation (independent loads, 2 barriers per batch), momentum, bf16
// store, ||c||^2. Also zeroes partials[] and the done counter for K2.

__global__ __launch_bounds__(256, 4)
void update_centers_kernel(const float* __restrict__ feats,
                           const float* __restrict__ centers,
                           const int* __restrict__ labels,
                           unsigned short* __restrict__ centers_bf,
                           float* __restrict__ sqn,
                           float* __restrict__ partials,
                           int* __restrict__ done) {
  __shared__ float sm[8];
  __shared__ int s_rows[MAXROWS];
  __shared__ int s_cnt;
  __shared__ float s_part[8][4];  // [row-in-batch][wave]
  __shared__ int s_anynz;
  int c = blockIdx.x;   // 0..1023
  int tid = threadIdx.x;
  int lane = tid & 63, wid = tid >> 6;
  int fi = tid;         // float4 index within the 256-float4 row

  // housekeeping for K2 (visible after this kernel's dispatch-boundary flush)
  if (tid == 0 && c < 768) partials[c] = 0.0f;
  if (tid == 1 && c == 0) *done = 0;

  if (c >= NCLS) {  // zero-pad rows so the MFMA tiles can load unguarded
    ((ushort4*)(centers_bf + (size_t)c * DIM))[fi] = make_ushort4(0, 0, 0, 0);
    return;
  }

  // ---- self-select rows of this class ----
  if (tid == 0) s_cnt = 0;
  __syncthreads();
  #pragma unroll 4
  for (int j = tid; j < BATCH; j += 256) {
    if (labels[j] == c) {
      int p = atomicAdd(&s_cnt, 1);
      if (p < MAXROWS) s_rows[p] = j;
    }
  }
  __syncthreads();
  int n = min(s_cnt, MAXROWS);

  const float4* f4 = (const float4*)feats;
  float4 acc = make_float4(0.f, 0.f, 0.f, 0.f);

  for (int b8 = 0; b8 < n; b8 += 8) {
    int m = min(8, n - b8);
    float4 v[8];
    #pragma unroll
    for (int j = 0; j < 8; ++j) {
      v[j] = make_float4(0.f, 0.f, 0.f, 0.f);
      if (j < m) v[j] = f4[(size_t)s_rows[b8 + j] * 256 + fi];
    }
    #pragma unroll
    for (int j = 0; j < 8; ++j) {
      float s = v[j].x * v[j].x + v[j].y * v[j].y + v[j].z * v[j].z + v[j].w * v[j].w;
      s = waveAllReduceAdd(s);
      if (lane == 0) s_part[j][wid] = s;
    }
    __syncthreads();
    #pragma unroll
    for (int j = 0; j < 8; ++j) {
      if (j < m) {
        float tot = s_part[j][0] + s_part[j][1] + s_part[j][2] + s_part[j][3];
        float w = 1.0f / fmaxf(sqrtf(tot), 1e-12f);
        acc.x += v[j].x * w; acc.y += v[j].y * w;
        acc.z += v[j].z * w; acc.w += v[j].w * w;
      }
    }
    __syncthreads();  // protect s_part reuse
  }

  float invc = 1.0f / fmaxf((float)n, 1.0f);
  float4 mean = make_float4(acc.x * invc, acc.y * invc, acc.z * invc, acc.w * invc);

  float4 cv = ((const float4*)(centers + (size_t)c * DIM))[fi];
  if (tid == 0) s_anynz = 0;
  __syncthreads();
  if (cv.x != 0.f || cv.y != 0.f || cv.z != 0.f || cv.w != 0.f) s_anynz = 1;
  __syncthreads();

  float4 o;
  if (s_anynz) {
    o = make_float4(0.9f * cv.x + 0.1f * mean.x, 0.9f * cv.y + 0.1f * mean.y,
                    0.9f * cv.z + 0.1f * mean.z, 0.9f * cv.w + 0.1f * mean.w);
  } else {
    o = mean;
  }
  if (n == 0) o = cv;

  ((ushort4*)(centers_bf + (size_t)c * DIM))[fi] =
      make_ushort4(f2bf(o.x), f2bf(o.y), f2bf(o.z), f2bf(o.w));

  float sq = blockReduce1(o.x * o.x + o.y * o.y + o.z * o.z + o.w * o.w, sm);
  if (tid == 0) sqn[c] = sq;
}

// ---------------- K2: inter (blocks 0..135) + intra (136..2183) + final -----
// Inter tiles placed FIRST so they overlap intra's HBM-bound phase.
// Intra keeps fv/av in registers (launch_bounds prevents the 32-VGPR
// spill/remat that killed round 1) and streams the center row in the
// distance loop. Last block to finish does the final combine in-kernel.

__global__ __launch_bounds__(256, 4)
void intra_inter_kernel(const float* __restrict__ feats,
                        const float* __restrict__ featsa,
                        const unsigned short* __restrict__ Cbf,
                        const int* __restrict__ labels,
                        const float* __restrict__ sq,
                        float* __restrict__ partials,
                        int* __restrict__ done,
                        float* __restrict__ out) {
  __shared__ float smr[8];
  __shared__ int s_last;
  int tid = threadIdx.x;  // 256
  int bid = blockIdx.x;

  if (bid >= INTER_TILES) {
    // ---- intra: wave-per-row ----
    int lane = tid & 63;
    int row = (bid - INTER_TILES) * 4 + (tid >> 6);
    const float4* f4 = (const float4*)(feats + (size_t)row * DIM);
    const float4* a4 = (const float4*)(featsa + (size_t)row * DIM);
    int lab = labels[row];
    const ushort4* c4 = (const ushort4*)(Cbf + (size_t)lab * DIM);

    float4 fv[4], av[4];
    float ssf = 0.f, ssa = 0.f;
    #pragma unroll
    for (int i = 0; i < 4; ++i) {
      fv[i] = f4[lane + 64 * i];
      av[i] = a4[lane + 64 * i];
      ssf += fv[i].x * fv[i].x + fv[i].y * fv[i].y + fv[i].z * fv[i].z + fv[i].w * fv[i].w;
      ssa += av[i].x * av[i].x + av[i].y * av[i].y + av[i].z * av[i].z + av[i].w * av[i].w;
    }
    ssf = waveAllReduceAdd(ssf);
    ssa = waveAllReduceAdd(ssa);
    float invf = 1.0f / fmaxf(sqrtf(ssf), 1e-12f);
    float inva = 1.0f / fmaxf(sqrtf(ssa), 1e-12f);

    float d2c = 0.f, d2a = 0.f;
    #pragma unroll
    for (int i = 0; i < 4; ++i) {
      ushort4 cvi = c4[lane + 64 * i];  // streamed from L2 (centers_bf is hot)
      float cx = __uint_as_float((unsigned)cvi.x << 16);
      float cy = __uint_as_float((unsigned)cvi.y << 16);
      float cz = __uint_as_float((unsigned)cvi.z << 16);
      float cw = __uint_as_float((unsigned)cvi.w << 16);
      float dx = fv[i].x * invf - cx, dy = fv[i].y * invf - cy;
      float dz = fv[i].z * invf - cz, dw = fv[i].w * invf - cw;
      d2c += dx * dx + dy * dy + dz * dz + dw * dw;
      float ex = av[i].x * inva - cx, ey = av[i].y * inva - cy;
      float ez = av[i].z * inva - cz, ew = av[i].w * inva - cw;
      d2a += ex * ex + ey * ey + ez * ez + ew * ew;
    }
    d2c = waveAllReduceAdd(d2c);
    d2a = waveAllReduceAdd(d2a);
    if (lane == 0) {
      int slot = row & 255;
      atomicAdd(&partials[slot], sqrtf(d2c));
      atomicAdd(&partials[256 + slot], sqrtf(d2a));
    }
  } else {
    // ---- inter: 64x64 tile, 2x2 mfma_f32_16x16x32_bf16 per wave ----
    int t = bid;  // 0..135
    int bi = 0;
    while (t >= 16 - bi) { t -= 16 - bi; ++bi; }
    int bj = bi + t;  // bi <= bj, upper triangle of 16x16 tile grid

    int w = tid >> 6;
    int wy = w >> 1, wx = w & 1;
    int lane = tid & 63;
    int m = lane & 15;
    int q = lane >> 4;

    int i0 = bi * 64 + wy * 32;
    int j0 = bj * 64 + wx * 32;

    const unsigned short* arow0 = Cbf + (size_t)(i0 + m) * DIM;
    const unsigned short* arow1 = Cbf + (size_t)(i0 + 16 + m) * DIM;
    const unsigned short* brow0 = Cbf + (size_t)(j0 + m) * DIM;
    const unsigned short* brow1 = Cbf + (size_t)(j0 + 16 + m) * DIM;

    f32x4 acc00 = {0.f, 0.f, 0.f, 0.f}, acc01 = acc00, acc10 = acc00, acc11 = acc00;

    #pragma unroll 4
    for (int k0 = 0; k0 < DIM; k0 += 32) {
      int ko = k0 + q * 8;
      bf16x8 a0 = *(const bf16x8*)(arow0 + ko);
      bf16x8 a1 = *(const bf16x8*)(arow1 + ko);
      bf16x8 b0 = *(const bf16x8*)(brow0 + ko);
      bf16x8 b1 = *(const bf16x8*)(brow1 + ko);
      acc00 = __builtin_amdgcn_mfma_f32_16x16x32_bf16(a0, b0, acc00, 0, 0, 0);
      acc01 = __builtin_amdgcn_mfma_f32_16x16x32_bf16(a0, b1, acc01, 0, 0, 0);
      acc10 = __builtin_amdgcn_mfma_f32_16x16x32_bf16(a1, b0, acc10, 0, 0, 0);
      acc11 = __builtin_amdgcn_mfma_f32_16x16x32_bf16(a1, b1, acc11, 0, 0, 0);
    }

    float local = 0.f;
    int colA = lane & 15;
    int rbase = (lane >> 4) * 4;
    #pragma unroll
    for (int si = 0; si < 2; ++si) {
      #pragma unroll
      for (int sj = 0; sj < 2; ++sj) {
        f32x4 a = (si == 0) ? (sj == 0 ? acc00 : acc01) : (sj == 0 ? acc10 : acc11);
        #pragma unroll
        for (int r = 0; r < 4; ++r) {
          int i = i0 + si * 16 + rbase + r;
          int j = j0 + sj * 16 + colA;
          if (j < NCLS && i < j) {
            float d2 = sq[i] + sq[j] - 2.0f * a[r];
            float d = sqrtf(fmaxf(d2, 0.0f));
            local += fmaxf(1.0f - d, 0.0f);
          }
        }
      }
    }
    float tot = blockReduce1(local, smr);
    if (tid == 0) atomicAdd(&partials[512 + ((bi * 16 + bj) & 255)], tot);
  }

  // ---- last-block final combine ----
  __threadfence();
  __syncthreads();  // drain this block's memory ops before signaling
  if (tid == 0) {
    int p = atomicAdd(done, 1);
    s_last = (p == GRID_B - 1);
  }
  __syncthreads();
  if (s_last) {
    __threadfence();
    float c = __hip_atomic_load(&partials[tid], __ATOMIC_RELAXED, __HIP_MEMORY_SCOPE_AGENT) +
              __hip_atomic_load(&partials[256 + tid], __ATOMIC_RELAXED, __HIP_MEMORY_SCOPE_AGENT);
    float e = __hip_atomic_load(&partials[512 + tid], __ATOMIC_RELAXED, __HIP_MEMORY_SCOPE_AGENT);
    c = blockReduce1(c, smr);
    e = blockReduce1(e, smr);
    if (tid == 0) {
      float intra = c * (1.0f / (float)BATCH);
      float inter = e / NPAIRS;
      out[0] = intra - 0.5f * inter;  // LAMBDA_INTRA=1, LAMBDA_INTER=0.5
    }
  }
}

// ---------------- launch ----------------

extern "C" void kernel_launch(void* const* d_in, const int* in_sizes, int n_in,
                              void* d_out, int out_size, void* d_ws, size_t ws_size,
                              hipStream_t stream) {
  const float* features     = (const float*)d_in[0];
  const float* features_adv = (const float*)d_in[1];
  const float* centers      = (const float*)d_in[2];
  const int*   labels       = (const int*)d_in[3];
  float* out = (float*)d_out;

  // ws layout: centers_bf[1024*1024 u16] | sqn[1000 f] | partials[768 f] | done[1 i]
  unsigned short* centers_bf = (unsigned short*)d_ws;
  float* sqn = (float*)(centers_bf + (size_t)NPAD * DIM);
  float* partials = sqn + NCLS;
  int* done = (int*)(partials + 768);

  hipLaunchKernelGGL(update_centers_kernel, dim3(NPAD), dim3(256), 0, stream,
                     features, centers, labels, centers_bf, sqn, partials, done);
  hipLaunchKernelGGL(intra_inter_kernel, dim3(GRID_B), dim3(256), 0, stream, features,
                     features_adv, centers_bf, labels, sqn, partials, done, out);
}

// Round 3
// 140.558 us; speedup vs baseline: 2.5052x; 2.5052x over previous
//
#include <hip/hip_runtime.h>
#include <math.h>

#define BATCH 8192
#define DIM 1024
#define NCLS 1000
#define NPAD 1024         // padded class rows for the bf16 center matrix
#define NPAIRS 499500.0f  // 1000*999/2
#define INTER_TILES 136   // 16*17/2 upper-triangle 64x64 tiles (placed FIRST)
#define INTRA_BLOCKS (BATCH / 4)
#define GRID_B (INTER_TILES + INTRA_BLOCKS)
#define MAXROWS 192       // max rows per class tracked (Poisson mean 8.2, max ~30)

typedef float  f32x4  __attribute__((ext_vector_type(4)));
typedef short  bf16x8 __attribute__((ext_vector_type(8)));

// ---------------- helpers ----------------

__device__ inline float waveAllReduceAdd(float x) {
  #pragma unroll
  for (int m = 32; m > 0; m >>= 1) x += __shfl_xor(x, m);
  return x;
}

// block (256 thr) reduce, broadcast; sm >= 8 floats
__device__ inline float blockReduce1(float x, float* sm) {
  x = waveAllReduceAdd(x);
  int lane = threadIdx.x & 63, wid = threadIdx.x >> 6;
  __syncthreads();
  if (lane == 0) sm[wid] = x;
  __syncthreads();
  return sm[0] + sm[1] + sm[2] + sm[3];
}

__device__ inline unsigned short f2bf(float f) {
  unsigned int u = __float_as_uint(f);
  u += 0x7FFFu + ((u >> 16) & 1u);  // RNE
  return (unsigned short)(u >> 16);
}

// ---------------- K1: center update, wave-per-row, barrier-free row loop -----
// Block c self-selects its class's rows by scanning the 32KB label array
// (L2 broadcast). Wave w then owns rows w, w+4, ...: loads the full row
// (4 float4/lane), wave-reduces the norm (no block barrier), stores invn[row]
// for the intra kernel, and accumulates the normalized row into a full-width
// per-wave partial center. One LDS combine at the end, then momentum, bf16
// store, ||c||^2. Also zeroes partials[].

__global__ __launch_bounds__(256, 4)
void update_centers_kernel(const float* __restrict__ feats,
                           const float* __restrict__ centers,
                           const int* __restrict__ labels,
                           unsigned short* __restrict__ centers_bf,
                           float* __restrict__ sqn,
                           float* __restrict__ invn,
                           float* __restrict__ partials) {
  __shared__ float sm[8];
  __shared__ int s_rows[MAXROWS];
  __shared__ int s_cnt;
  __shared__ int s_anynz;
  __shared__ float4 s_acc[4][256];  // 16KB: per-wave full-width partial center
  int c = blockIdx.x;   // 0..1023
  int tid = threadIdx.x;
  int lane = tid & 63, w = tid >> 6;
  int fi = tid;         // float4 index for full-row ops

  if (tid == 0 && c < 768) partials[c] = 0.0f;

  if (c >= NCLS) {  // zero-pad rows so the MFMA tiles can load unguarded
    ((ushort4*)(centers_bf + (size_t)c * DIM))[fi] = make_ushort4(0, 0, 0, 0);
    return;
  }

  // ---- self-select rows of this class ----
  if (tid == 0) { s_cnt = 0; s_anynz = 0; }
  __syncthreads();
  #pragma unroll 4
  for (int j = tid; j < BATCH; j += 256) {
    if (labels[j] == c) {
      int p = atomicAdd(&s_cnt, 1);
      if (p < MAXROWS) s_rows[p] = j;
    }
  }
  __syncthreads();
  int n = min(s_cnt, MAXROWS);

  // ---- wave-per-row accumulation (no barriers) ----
  float4 acc[4];
  #pragma unroll
  for (int i = 0; i < 4; ++i) acc[i] = make_float4(0.f, 0.f, 0.f, 0.f);

  for (int t = w; t < n; t += 4) {
    int r = s_rows[t];
    const float4* rp = (const float4*)(feats + (size_t)r * DIM);
    float4 v[4];
    #pragma unroll
    for (int i = 0; i < 4; ++i) v[i] = rp[lane + 64 * i];
    float ss = 0.f;
    #pragma unroll
    for (int i = 0; i < 4; ++i)
      ss += v[i].x * v[i].x + v[i].y * v[i].y + v[i].z * v[i].z + v[i].w * v[i].w;
    ss = waveAllReduceAdd(ss);
    float iw = 1.0f / fmaxf(sqrtf(ss), 1e-12f);
    if (lane == 0) invn[r] = iw;   // free by-product for the intra kernel
    #pragma unroll
    for (int i = 0; i < 4; ++i) {
      acc[i].x += v[i].x * iw; acc[i].y += v[i].y * iw;
      acc[i].z += v[i].z * iw; acc[i].w += v[i].w * iw;
    }
  }

  // ---- combine the 4 waves' partials ----
  #pragma unroll
  for (int i = 0; i < 4; ++i) s_acc[w][lane + 64 * i] = acc[i];
  float4 cv = ((const float4*)(centers + (size_t)c * DIM))[fi];
  if (cv.x != 0.f || cv.y != 0.f || cv.z != 0.f || cv.w != 0.f) s_anynz = 1;
  __syncthreads();
  float4 a0 = s_acc[0][fi], a1 = s_acc[1][fi], a2 = s_acc[2][fi], a3 = s_acc[3][fi];
  float4 sum = make_float4(a0.x + a1.x + a2.x + a3.x, a0.y + a1.y + a2.y + a3.y,
                           a0.z + a1.z + a2.z + a3.z, a0.w + a1.w + a2.w + a3.w);

  float invc = 1.0f / fmaxf((float)n, 1.0f);
  float4 mean = make_float4(sum.x * invc, sum.y * invc, sum.z * invc, sum.w * invc);

  float4 o;
  if (s_anynz) {
    o = make_float4(0.9f * cv.x + 0.1f * mean.x, 0.9f * cv.y + 0.1f * mean.y,
                    0.9f * cv.z + 0.1f * mean.z, 0.9f * cv.w + 0.1f * mean.w);
  } else {
    o = mean;
  }
  if (n == 0) o = cv;

  ((ushort4*)(centers_bf + (size_t)c * DIM))[fi] =
      make_ushort4(f2bf(o.x), f2bf(o.y), f2bf(o.z), f2bf(o.w));

  float sq = blockReduce1(o.x * o.x + o.y * o.y + o.z * o.z + o.w * o.w, sm);
  if (tid == 0) sqn[c] = sq;
}

// ---------------- K2: inter (blocks 0..135) + intra (136..2183) --------------
// Inter tiles FIRST so the MFMA work overlaps intra's HBM-bound phase instead
// of forming a low-occupancy tail.
// Intra uses the dot-product identity ||f_hat - c||^2 = 1 + ||c||^2 - 2*invf*(f.c):
// three streaming accumulators, every load consumed immediately (no live
// tiles for the compiler to spill/rematerialize), f-norm precomputed in K1.

__global__ __launch_bounds__(256, 4)
void intra_inter_kernel(const float* __restrict__ feats,
                        const float* __restrict__ featsa,
                        const unsigned short* __restrict__ Cbf,
                        const int* __restrict__ labels,
                        const float* __restrict__ sq,
                        const float* __restrict__ invn,
                        float* __restrict__ partials) {
  __shared__ float smr[8];
  int tid = threadIdx.x;  // 256
  int bid = blockIdx.x;

  if (bid >= INTER_TILES) {
    // ---- intra: wave-per-row, pure streaming dot-products ----
    int lane = tid & 63;
    int row = (bid - INTER_TILES) * 4 + (tid >> 6);
    const float4* f4 = (const float4*)(feats + (size_t)row * DIM);
    const float4* a4 = (const float4*)(featsa + (size_t)row * DIM);
    int lab = labels[row];
    float invf = invn[row];
    const ushort4* c4 = (const ushort4*)(Cbf + (size_t)lab * DIM);

    float dotf = 0.f, dota = 0.f, ssa = 0.f;
    #pragma unroll
    for (int i = 0; i < 4; ++i) {
      float4 fv = f4[lane + 64 * i];
      float4 av = a4[lane + 64 * i];
      ushort4 cvi = c4[lane + 64 * i];
      float cx = __uint_as_float((unsigned)cvi.x << 16);
      float cy = __uint_as_float((unsigned)cvi.y << 16);
      float cz = __uint_as_float((unsigned)cvi.z << 16);
      float cw = __uint_as_float((unsigned)cvi.w << 16);
      dotf += fv.x * cx + fv.y * cy + fv.z * cz + fv.w * cw;
      dota += av.x * cx + av.y * cy + av.z * cz + av.w * cw;
      ssa  += av.x * av.x + av.y * av.y + av.z * av.z + av.w * av.w;
    }
    dotf = waveAllReduceAdd(dotf);
    dota = waveAllReduceAdd(dota);
    ssa  = waveAllReduceAdd(ssa);
    float inva = 1.0f / fmaxf(sqrtf(ssa), 1e-12f);
    float sqc = sq[lab];
    float d2c = 1.0f + sqc - 2.0f * invf * dotf;
    float d2a = 1.0f + sqc - 2.0f * inva * dota;
    if (lane == 0) {
      int slot = row & 255;
      atomicAdd(&partials[slot], sqrtf(fmaxf(d2c, 0.0f)));
      atomicAdd(&partials[256 + slot], sqrtf(fmaxf(d2a, 0.0f)));
    }
  } else {
    // ---- inter: 64x64 tile, 2x2 mfma_f32_16x16x32_bf16 per wave ----
    int t = bid;  // 0..135
    int bi = 0;
    while (t >= 16 - bi) { t -= 16 - bi; ++bi; }
    int bj = bi + t;  // bi <= bj, upper triangle of 16x16 tile grid

    int w = tid >> 6;
    int wy = w >> 1, wx = w & 1;
    int lane = tid & 63;
    int m = lane & 15;
    int q = lane >> 4;

    int i0 = bi * 64 + wy * 32;
    int j0 = bj * 64 + wx * 32;

    const unsigned short* arow0 = Cbf + (size_t)(i0 + m) * DIM;
    const unsigned short* arow1 = Cbf + (size_t)(i0 + 16 + m) * DIM;
    const unsigned short* brow0 = Cbf + (size_t)(j0 + m) * DIM;
    const unsigned short* brow1 = Cbf + (size_t)(j0 + 16 + m) * DIM;

    f32x4 acc00 = {0.f, 0.f, 0.f, 0.f}, acc01 = acc00, acc10 = acc00, acc11 = acc00;

    #pragma unroll 4
    for (int k0 = 0; k0 < DIM; k0 += 32) {
      int ko = k0 + q * 8;
      bf16x8 a0 = *(const bf16x8*)(arow0 + ko);
      bf16x8 a1 = *(const bf16x8*)(arow1 + ko);
      bf16x8 b0 = *(const bf16x8*)(brow0 + ko);
      bf16x8 b1 = *(const bf16x8*)(brow1 + ko);
      acc00 = __builtin_amdgcn_mfma_f32_16x16x32_bf16(a0, b0, acc00, 0, 0, 0);
      acc01 = __builtin_amdgcn_mfma_f32_16x16x32_bf16(a0, b1, acc01, 0, 0, 0);
      acc10 = __builtin_amdgcn_mfma_f32_16x16x32_bf16(a1, b0, acc10, 0, 0, 0);
      acc11 = __builtin_amdgcn_mfma_f32_16x16x32_bf16(a1, b1, acc11, 0, 0, 0);
    }

    float local = 0.f;
    int colA = lane & 15;
    int rbase = (lane >> 4) * 4;
    #pragma unroll
    for (int si = 0; si < 2; ++si) {
      #pragma unroll
      for (int sj = 0; sj < 2; ++sj) {
        f32x4 a = (si == 0) ? (sj == 0 ? acc00 : acc01) : (sj == 0 ? acc10 : acc11);
        #pragma unroll
        for (int r = 0; r < 4; ++r) {
          int i = i0 + si * 16 + rbase + r;
          int j = j0 + sj * 16 + colA;
          if (j < NCLS && i < j) {
            float d2 = sq[i] + sq[j] - 2.0f * a[r];
            float d = sqrtf(fmaxf(d2, 0.0f));
            local += fmaxf(1.0f - d, 0.0f);
          }
        }
      }
    }
    float tot = blockReduce1(local, smr);
    if (tid == 0) atomicAdd(&partials[512 + ((bi * 16 + bj) & 255)], tot);
  }
}

// ---------------- K3: final combine ----------------

__global__ void final_kernel(const float* __restrict__ partials, float* __restrict__ out) {
  __shared__ float sm[8];
  int t = threadIdx.x;  // 256
  float c = partials[t] + partials[256 + t];
  float e = partials[512 + t];
  c = blockReduce1(c, sm);
  e = blockReduce1(e, sm);
  if (t == 0) {
    float intra = c * (1.0f / (float)BATCH);
    float inter = e / NPAIRS;
    out[0] = intra - 0.5f * inter;  // LAMBDA_INTRA=1, LAMBDA_INTER=0.5
  }
}

// ---------------- launch ----------------

extern "C" void kernel_launch(void* const* d_in, const int* in_sizes, int n_in,
                              void* d_out, int out_size, void* d_ws, size_t ws_size,
                              hipStream_t stream) {
  const float* features     = (const float*)d_in[0];
  const float* features_adv = (const float*)d_in[1];
  const float* centers      = (const float*)d_in[2];
  const int*   labels       = (const int*)d_in[3];
  float* out = (float*)d_out;

  // ws layout: centers_bf[1024*1024 u16] | sqn[1000 f] | invn[8192 f] | partials[768 f]
  unsigned short* centers_bf = (unsigned short*)d_ws;
  float* sqn = (float*)(centers_bf + (size_t)NPAD * DIM);
  float* invn = sqn + NCLS;
  float* partials = invn + BATCH;

  hipLaunchKernelGGL(update_centers_kernel, dim3(NPAD), dim3(256), 0, stream,
                     features, centers, labels, centers_bf, sqn, invn, partials);
  hipLaunchKernelGGL(intra_inter_kernel, dim3(GRID_B), dim3(256), 0, stream, features,
                     features_adv, centers_bf, labels, sqn, invn, partials);
  hipLaunchKernelGGL(final_kernel, dim3(1), dim3(256), 0, stream, partials, out);
}

// Round 4
// 139.707 us; speedup vs baseline: 2.5205x; 1.0061x over previous
//
#include <hip/hip_runtime.h>
#include <math.h>

#define BATCH 8192
#define DIM 1024
#define NCLS 1000
#define NPAD 1024         // padded class rows for the bf16 center matrix
#define NPAIRS 499500.0f  // 1000*999/2
#define INTER_TILES 136   // 16*17/2 upper-triangle 64x64 tiles
#define MAXROWS 192       // max rows per class tracked (Poisson mean 8.2, max ~35)

typedef float  f32x4  __attribute__((ext_vector_type(4)));
typedef short  bf16x8 __attribute__((ext_vector_type(8)));

// ---------------- helpers ----------------

__device__ inline float waveAllReduceAdd(float x) {
  #pragma unroll
  for (int m = 32; m > 0; m >>= 1) x += __shfl_xor(x, m);
  return x;
}

// block (256 thr) reduce, broadcast; sm >= 8 floats
__device__ inline float blockReduce1(float x, float* sm) {
  x = waveAllReduceAdd(x);
  int lane = threadIdx.x & 63, wid = threadIdx.x >> 6;
  __syncthreads();
  if (lane == 0) sm[wid] = x;
  __syncthreads();
  return sm[0] + sm[1] + sm[2] + sm[3];
}

__device__ inline unsigned short f2bf(float f) {
  unsigned int u = __float_as_uint(f);
  u += 0x7FFFu + ((u >> 16) & 1u);  // RNE
  return (unsigned short)(u >> 16);
}

// ---------------- K1: fused center update + intra losses ---------------------
// Block c self-selects its class's rows (label scan, L2 broadcast).
// Pass 1 (wave-per-row, barrier-free): row norm -> accumulate normalized row
// into per-wave full-width partial center; iw cached in LDS.
// Combine -> momentum -> c_new kept f32 in LDS + stored bf16 + ||c||^2.
// Pass 2 (wave-per-row): d2 = 1 + ||c||^2 - 2*iw*(f.c_new); clean rows re-read
// from L1/L2 (just touched), adv rows streamed once (norm+dot in one pass).
// Per-class private output slots -> no atomics, no zeroing pass.

__global__ __launch_bounds__(256, 4)
void update_centers_intra_kernel(const float* __restrict__ feats,
                                 const float* __restrict__ featsa,
                                 const float* __restrict__ centers,
                                 const int* __restrict__ labels,
                                 unsigned short* __restrict__ centers_bf,
                                 float* __restrict__ sqn,
                                 float* __restrict__ pclean,
                                 float* __restrict__ padv) {
  __shared__ float sm[8];
  __shared__ int s_rows[MAXROWS];
  __shared__ float s_iw[MAXROWS];
  __shared__ int s_cnt;
  __shared__ int s_anynz;
  __shared__ float4 s_acc[4][256];  // 16KB per-wave full-width partial center
  __shared__ float4 s_c[256];       // 4KB: c_new (f32) for pass-2 dots
  int c = blockIdx.x;   // 0..1023
  int tid = threadIdx.x;
  int lane = tid & 63, w = tid >> 6;
  int fi = tid;         // float4 index for full-row ops

  if (c >= NCLS) {  // zero-pad rows so the MFMA tiles can load unguarded
    ((ushort4*)(centers_bf + (size_t)c * DIM))[fi] = make_ushort4(0, 0, 0, 0);
    return;
  }

  // ---- self-select rows of this class ----
  if (tid == 0) { s_cnt = 0; s_anynz = 0; }
  __syncthreads();
  #pragma unroll 4
  for (int j = tid; j < BATCH; j += 256) {
    if (labels[j] == c) {
      int p = atomicAdd(&s_cnt, 1);
      if (p < MAXROWS) s_rows[p] = j;
    }
  }
  __syncthreads();
  int n = min(s_cnt, MAXROWS);

  // ---- pass 1: wave-per-row norm + normalized accumulation (no barriers) ----
  float4 acc[4];
  #pragma unroll
  for (int i = 0; i < 4; ++i) acc[i] = make_float4(0.f, 0.f, 0.f, 0.f);

  for (int t = w; t < n; t += 4) {
    int r = s_rows[t];
    const float4* rp = (const float4*)(feats + (size_t)r * DIM);
    float4 v[4];
    #pragma unroll
    for (int i = 0; i < 4; ++i) v[i] = rp[lane + 64 * i];
    float ss = 0.f;
    #pragma unroll
    for (int i = 0; i < 4; ++i)
      ss += v[i].x * v[i].x + v[i].y * v[i].y + v[i].z * v[i].z + v[i].w * v[i].w;
    ss = waveAllReduceAdd(ss);
    float iw = 1.0f / fmaxf(sqrtf(ss), 1e-12f);
    if (lane == 0) s_iw[t] = iw;
    #pragma unroll
    for (int i = 0; i < 4; ++i) {
      acc[i].x += v[i].x * iw; acc[i].y += v[i].y * iw;
      acc[i].z += v[i].z * iw; acc[i].w += v[i].w * iw;
    }
  }

  // ---- combine the 4 waves' partials, momentum, store ----
  #pragma unroll
  for (int i = 0; i < 4; ++i) s_acc[w][lane + 64 * i] = acc[i];
  float4 cv = ((const float4*)(centers + (size_t)c * DIM))[fi];
  if (cv.x != 0.f || cv.y != 0.f || cv.z != 0.f || cv.w != 0.f) s_anynz = 1;
  __syncthreads();
  float4 a0 = s_acc[0][fi], a1 = s_acc[1][fi], a2 = s_acc[2][fi], a3 = s_acc[3][fi];
  float4 sum = make_float4(a0.x + a1.x + a2.x + a3.x, a0.y + a1.y + a2.y + a3.y,
                           a0.z + a1.z + a2.z + a3.z, a0.w + a1.w + a2.w + a3.w);

  float invc = 1.0f / fmaxf((float)n, 1.0f);
  float4 mean = make_float4(sum.x * invc, sum.y * invc, sum.z * invc, sum.w * invc);

  float4 o;
  if (s_anynz) {
    o = make_float4(0.9f * cv.x + 0.1f * mean.x, 0.9f * cv.y + 0.1f * mean.y,
                    0.9f * cv.z + 0.1f * mean.z, 0.9f * cv.w + 0.1f * mean.w);
  } else {
    o = mean;
  }
  if (n == 0) o = cv;

  ((ushort4*)(centers_bf + (size_t)c * DIM))[fi] =
      make_ushort4(f2bf(o.x), f2bf(o.y), f2bf(o.z), f2bf(o.w));
  s_c[fi] = o;

  float sq = blockReduce1(o.x * o.x + o.y * o.y + o.z * o.z + o.w * o.w, sm);
  if (tid == 0) sqn[c] = sq;
  __syncthreads();  // s_c visible to all waves before pass 2

  // ---- pass 2a: clean-row dots (rows hot in L1/L2) ----
  float sumc = 0.f;
  for (int t = w; t < n; t += 4) {
    int r = s_rows[t];
    const float4* rp = (const float4*)(feats + (size_t)r * DIM);
    float dot = 0.f;
    #pragma unroll
    for (int i = 0; i < 4; ++i) {
      float4 v = rp[lane + 64 * i];
      float4 cc = s_c[lane + 64 * i];
      dot += v.x * cc.x + v.y * cc.y + v.z * cc.z + v.w * cc.w;
    }
    dot = waveAllReduceAdd(dot);
    if (lane == 0) {
      float d2 = 1.0f + sq - 2.0f * s_iw[t] * dot;
      sumc += sqrtf(fmaxf(d2, 0.0f));
    }
  }

  // ---- pass 2b: adv rows, norm + dot in one streamed pass ----
  float suma = 0.f;
  for (int t = w; t < n; t += 4) {
    int r = s_rows[t];
    const float4* ap = (const float4*)(featsa + (size_t)r * DIM);
    float dot = 0.f, ssa = 0.f;
    #pragma unroll
    for (int i = 0; i < 4; ++i) {
      float4 v = ap[lane + 64 * i];
      float4 cc = s_c[lane + 64 * i];
      dot += v.x * cc.x + v.y * cc.y + v.z * cc.z + v.w * cc.w;
      ssa += v.x * v.x + v.y * v.y + v.z * v.z + v.w * v.w;
    }
    dot = waveAllReduceAdd(dot);
    ssa = waveAllReduceAdd(ssa);
    if (lane == 0) {
      float inva = 1.0f / fmaxf(sqrtf(ssa), 1e-12f);
      float d2 = 1.0f + sq - 2.0f * inva * dot;
      suma += sqrtf(fmaxf(d2, 0.0f));
    }
  }

  float totc = blockReduce1(sumc, sm);  // only lane0s carry nonzero -> correct sum
  float tota = blockReduce1(suma, sm);
  if (tid == 0) { pclean[c] = totc; padv[c] = tota; }
}

// ---------------- K2: inter loss, 136 upper-triangle 64x64 MFMA tiles --------

__global__ __launch_bounds__(256, 4)
void inter_mfma_kernel(const unsigned short* __restrict__ Cbf,
                       const float* __restrict__ sq,
                       float* __restrict__ pinter) {
  __shared__ float smr[8];
  int tid = threadIdx.x;  // 256
  int bid = blockIdx.x;   // 0..135

  int t = bid;
  int bi = 0;
  while (t >= 16 - bi) { t -= 16 - bi; ++bi; }
  int bj = bi + t;  // bi <= bj, upper triangle of 16x16 tile grid

  int w = tid >> 6;
  int wy = w >> 1, wx = w & 1;
  int lane = tid & 63;
  int m = lane & 15;
  int q = lane >> 4;

  int i0 = bi * 64 + wy * 32;
  int j0 = bj * 64 + wx * 32;

  const unsigned short* arow0 = Cbf + (size_t)(i0 + m) * DIM;
  const unsigned short* arow1 = Cbf + (size_t)(i0 + 16 + m) * DIM;
  const unsigned short* brow0 = Cbf + (size_t)(j0 + m) * DIM;
  const unsigned short* brow1 = Cbf + (size_t)(j0 + 16 + m) * DIM;

  f32x4 acc00 = {0.f, 0.f, 0.f, 0.f}, acc01 = acc00, acc10 = acc00, acc11 = acc00;

  #pragma unroll 4
  for (int k0 = 0; k0 < DIM; k0 += 32) {
    int ko = k0 + q * 8;
    bf16x8 a0 = *(const bf16x8*)(arow0 + ko);
    bf16x8 a1 = *(const bf16x8*)(arow1 + ko);
    bf16x8 b0 = *(const bf16x8*)(brow0 + ko);
    bf16x8 b1 = *(const bf16x8*)(brow1 + ko);
    acc00 = __builtin_amdgcn_mfma_f32_16x16x32_bf16(a0, b0, acc00, 0, 0, 0);
    acc01 = __builtin_amdgcn_mfma_f32_16x16x32_bf16(a0, b1, acc01, 0, 0, 0);
    acc10 = __builtin_amdgcn_mfma_f32_16x16x32_bf16(a1, b0, acc10, 0, 0, 0);
    acc11 = __builtin_amdgcn_mfma_f32_16x16x32_bf16(a1, b1, acc11, 0, 0, 0);
  }

  float local = 0.f;
  int colA = lane & 15;
  int rbase = (lane >> 4) * 4;
  #pragma unroll
  for (int si = 0; si < 2; ++si) {
    #pragma unroll
    for (int sj = 0; sj < 2; ++sj) {
      f32x4 a = (si == 0) ? (sj == 0 ? acc00 : acc01) : (sj == 0 ? acc10 : acc11);
      #pragma unroll
      for (int r = 0; r < 4; ++r) {
        int i = i0 + si * 16 + rbase + r;
        int j = j0 + sj * 16 + colA;
        if (j < NCLS && i < j) {
          float d2 = sq[i] + sq[j] - 2.0f * a[r];
          float d = sqrtf(fmaxf(d2, 0.0f));
          local += fmaxf(1.0f - d, 0.0f);
        }
      }
    }
  }
  float tot = blockReduce1(local, smr);
  if (tid == 0) pinter[bid] = tot;  // private slot, no atomic, no zeroing
}

// ---------------- K3: final combine ----------------

__global__ void final_kernel(const float* __restrict__ pclean,
                             const float* __restrict__ padv,
                             const float* __restrict__ pinter,
                             float* __restrict__ out) {
  __shared__ float sm[8];
  int t = threadIdx.x;  // 256
  float ci = 0.f;
  for (int i = t; i < NCLS; i += 256) ci += pclean[i] + padv[i];
  float e = (t < INTER_TILES) ? pinter[t] : 0.f;
  ci = blockReduce1(ci, sm);
  e = blockReduce1(e, sm);
  if (t == 0) {
    float intra = ci * (1.0f / (float)BATCH);
    float inter = e / NPAIRS;
    out[0] = intra - 0.5f * inter;  // LAMBDA_INTRA=1, LAMBDA_INTER=0.5
  }
}

// ---------------- launch ----------------

extern "C" void kernel_launch(void* const* d_in, const int* in_sizes, int n_in,
                              void* d_out, int out_size, void* d_ws, size_t ws_size,
                              hipStream_t stream) {
  const float* features     = (const float*)d_in[0];
  const float* features_adv = (const float*)d_in[1];
  const float* centers      = (const float*)d_in[2];
  const int*   labels       = (const int*)d_in[3];
  float* out = (float*)d_out;

  // ws layout: centers_bf[1024*1024 u16] | sqn[1024 f] | pclean[1024 f] |
  //            padv[1024 f] | pinter[256 f]
  unsigned short* centers_bf = (unsigned short*)d_ws;
  float* sqn = (float*)(centers_bf + (size_t)NPAD * DIM);
  float* pclean = sqn + 1024;
  float* padv = pclean + 1024;
  float* pinter = padv + 1024;

  hipLaunchKernelGGL(update_centers_intra_kernel, dim3(NPAD), dim3(256), 0, stream,
                     features, features_adv, centers, labels, centers_bf, sqn,
                     pclean, padv);
  hipLaunchKernelGGL(inter_mfma_kernel, dim3(INTER_TILES), dim3(256), 0, stream,
                     centers_bf, sqn, pinter);
  hipLaunchKernelGGL(final_kernel, dim3(1), dim3(256), 0, stream, pclean, padv,
                     pinter, out);
}